// Round 1
// baseline (74.676 us; speedup 1.0000x reference)
//
#include <hip/hip_runtime.h>
#include <math.h>

#define HDIM 1024
#define VDIM 50257
#define LDIM 512

// ws layout (floats):
// [0,512)        attention logits
// [512,1024)     attention weights
// [1024,2048)    attn_applied (atomic accum, zeroed by k_softmax_att)
// [2048,3072)    x (GRU input)
// [3072,6144)    gi
// [6144,9216)    gh
// [9216,10240)   h_new
// [10240,10240+V) output logits
// [10240+V, +2)  max, log(sumexp)
#define WS_ATTLOG 0
#define WS_ATTW   512
#define WS_CTX    1024
#define WS_X      2048
#define WS_GI     3072
#define WS_GH     6144
#define WS_HNEW   9216
#define WS_OLOG   10240
#define WS_RED    (10240 + VDIM)

__device__ __forceinline__ float waveSum(float v) {
#pragma unroll
    for (int o = 32; o; o >>= 1) v += __shfl_down(v, o, 64);
    return v;
}

// ---- K1: attention logits: ws[row] = dot(cat(emb_row, h), attn_W[row]) + attn_b[row]
__global__ __launch_bounds__(64) void k_att(const int* idx_p, const float* hidden,
                                            const float* emb, const float* attn_W,
                                            const float* attn_b, float* ws) {
    int row = blockIdx.x;
    int lane = threadIdx.x;
    const float4* w4 = (const float4*)(attn_W + (size_t)row * 2 * HDIM);
    const float4* e4 = (const float4*)(emb + (size_t)idx_p[0] * HDIM);
    const float4* h4 = (const float4*)hidden;
    float acc = 0.f;
#pragma unroll
    for (int k = 0; k < 8; ++k) {
        int c = lane + 64 * k;                 // float4 chunk 0..511
        float4 w = w4[c];
        float4 x = (c < 256) ? e4[c] : h4[c - 256];
        acc += w.x * x.x + w.y * x.y + w.z * x.z + w.w * x.w;
    }
    acc = waveSum(acc);
    if (lane == 0) ws[WS_ATTLOG + row] = acc + attn_b[row];
}

// ---- K2: softmax over 512 logits; also zero the context accumulator
__global__ __launch_bounds__(512) void k_softmax_att(float* ws, float* out_attn) {
    __shared__ float sred[8];
    int t = threadIdx.x, lane = t & 63, wid = t >> 6;
    float v = ws[WS_ATTLOG + t];
    float m = v;
#pragma unroll
    for (int o = 32; o; o >>= 1) m = fmaxf(m, __shfl_down(m, o, 64));
    if (lane == 0) sred[wid] = m;
    __syncthreads();
    if (t < 8) {
        float x = sred[t];
#pragma unroll
        for (int o = 4; o; o >>= 1) x = fmaxf(x, __shfl_down(x, o, 64));
        if (t == 0) sred[0] = x;
    }
    __syncthreads();
    m = sred[0];
    __syncthreads();
    float e = expf(v - m);
    float s = waveSum(e);
    if (lane == 0) sred[wid] = s;
    __syncthreads();
    if (t < 8) {
        float x = sred[t];
#pragma unroll
        for (int o = 4; o; o >>= 1) x += __shfl_down(x, o, 64);
        if (t == 0) sred[0] = x;
    }
    __syncthreads();
    float w = e / sred[0];
    ws[WS_ATTW + t] = w;
    out_attn[t] = w;
    // zero attn_applied accumulator (1024 floats, 512 threads)
    ws[WS_CTX + t] = 0.f;
    ws[WS_CTX + 512 + t] = 0.f;
}

// ---- K3: attn_applied[h] = sum_l w[l]*enc[l][h]; split L 16-way, atomic accum
__global__ __launch_bounds__(256) void k_ctx(const float* enc, float* ws) {
    int lc = blockIdx.x & 15;
    int hb = blockIdx.x >> 4;
    int h = hb * 256 + threadIdx.x;
    const float* w = ws + WS_ATTW;
    float acc = 0.f;
    int l0 = lc * 32;
#pragma unroll 8
    for (int l = l0; l < l0 + 32; ++l)
        acc += w[l] * enc[(size_t)l * HDIM + h];
    atomicAdd(&ws[WS_CTX + h], acc);
}

// ---- K4: x[j] = relu(dot(cat(emb_row, attn_applied), comb_W[j]) + comb_b[j])
__global__ __launch_bounds__(256) void k_combine(const int* idx_p, const float* emb,
                                                 const float* comb_W, const float* comb_b,
                                                 float* ws) {
    int wid = threadIdx.x >> 6, lane = threadIdx.x & 63;
    int j = blockIdx.x * 4 + wid;
    const float4* w4 = (const float4*)(comb_W + (size_t)j * 2 * HDIM);
    const float4* e4 = (const float4*)(emb + (size_t)idx_p[0] * HDIM);
    const float4* c4 = (const float4*)(ws + WS_CTX);
    float acc = 0.f;
#pragma unroll
    for (int k = 0; k < 8; ++k) {
        int c = lane + 64 * k;
        float4 w = w4[c];
        float4 x = (c < 256) ? e4[c] : c4[c - 256];
        acc += w.x * x.x + w.y * x.y + w.z * x.z + w.w * x.w;
    }
    acc = waveSum(acc);
    if (lane == 0) ws[WS_X + j] = fmaxf(acc + comb_b[j], 0.f);
}

// ---- K5: gi[k]=dot(x,W_ih[k])+b_ih[k]; gh[k]=dot(h,W_hh[k])+b_hh[k]
__global__ __launch_bounds__(256) void k_gru(const float* hidden, const float* W_ih,
                                             const float* W_hh, const float* b_ih,
                                             const float* b_hh, float* ws) {
    int wid = threadIdx.x >> 6, lane = threadIdx.x & 63;
    int g = blockIdx.x * 4 + wid;  // 0..6143
    const float* vec; const float* W; const float* b; float* out; int k;
    if (g < 3072) { vec = ws + WS_X; W = W_ih; b = b_ih; out = ws + WS_GI; k = g; }
    else          { vec = hidden;    W = W_hh; b = b_hh; out = ws + WS_GH; k = g - 3072; }
    const float4* w4 = (const float4*)(W + (size_t)k * HDIM);
    const float4* v4 = (const float4*)vec;
    float acc = 0.f;
#pragma unroll
    for (int q = 0; q < 4; ++q) {
        int c = lane + 64 * q;
        float4 w = w4[c]; float4 x = v4[c];
        acc += w.x * x.x + w.y * x.y + w.z * x.z + w.w * x.w;
    }
    acc = waveSum(acc);
    if (lane == 0) out[k] = acc + b[k];
}

// ---- K6: GRU gate fusion -> h_new
__global__ __launch_bounds__(256) void k_gate(const float* hidden, float* ws, float* out_h) {
    int i = blockIdx.x * 256 + threadIdx.x;
    float gi_r = ws[WS_GI + i],        gh_r = ws[WS_GH + i];
    float gi_z = ws[WS_GI + 1024 + i], gh_z = ws[WS_GH + 1024 + i];
    float gi_n = ws[WS_GI + 2048 + i], gh_n = ws[WS_GH + 2048 + i];
    float r = 1.f / (1.f + expf(-(gi_r + gh_r)));
    float z = 1.f / (1.f + expf(-(gi_z + gh_z)));
    float n = tanhf(gi_n + r * gh_n);
    float hn = (1.f - z) * n + z * hidden[i];
    ws[WS_HNEW + i] = hn;
    out_h[i] = hn;
}

// ---- K7: output logits: ws[WS_OLOG+v] = dot(h_new, out_W[v]) + out_b[v]
__global__ __launch_bounds__(256) void k_out(const float* out_W, const float* out_b,
                                             float* ws) {
    int wid = threadIdx.x >> 6, lane = threadIdx.x & 63;
    int v = blockIdx.x * 4 + wid;
    if (v >= VDIM) return;
    const float4* w4 = (const float4*)(out_W + (size_t)v * HDIM);
    const float4* h4 = (const float4*)(ws + WS_HNEW);
    float acc = 0.f;
#pragma unroll
    for (int q = 0; q < 4; ++q) {
        int c = lane + 64 * q;
        float4 w = w4[c]; float4 x = h4[c];
        acc += w.x * x.x + w.y * x.y + w.z * x.z + w.w * x.w;
    }
    acc = waveSum(acc);
    if (lane == 0) ws[WS_OLOG + v] = acc + out_b[v];
}

// ---- K8: reduce max and log-sum-exp over V logits
__global__ __launch_bounds__(1024) void k_red(float* ws) {
    __shared__ float sred[16];
    int t = threadIdx.x, lane = t & 63, wid = t >> 6;
    const float* lg = ws + WS_OLOG;
    float m = -INFINITY;
    for (int i = t; i < VDIM; i += 1024) m = fmaxf(m, lg[i]);
#pragma unroll
    for (int o = 32; o; o >>= 1) m = fmaxf(m, __shfl_down(m, o, 64));
    if (lane == 0) sred[wid] = m;
    __syncthreads();
    if (t < 16) {
        float x = sred[t];
#pragma unroll
        for (int o = 8; o; o >>= 1) x = fmaxf(x, __shfl_down(x, o, 64));
        if (t == 0) sred[0] = x;
    }
    __syncthreads();
    m = sred[0];
    __syncthreads();
    float s = 0.f;
    for (int i = t; i < VDIM; i += 1024) s += expf(lg[i] - m);
#pragma unroll
    for (int o = 32; o; o >>= 1) s += __shfl_down(s, o, 64);
    if (lane == 0) sred[wid] = s;
    __syncthreads();
    if (t < 16) {
        float x = sred[t];
#pragma unroll
        for (int o = 8; o; o >>= 1) x += __shfl_down(x, o, 64);
        if (t == 0) { ws[WS_RED] = m; ws[WS_RED + 1] = logf(x); }
    }
}

// ---- K9: finalize log_softmax
__global__ __launch_bounds__(256) void k_final(const float* ws, float* out) {
    int i = blockIdx.x * 256 + threadIdx.x;
    if (i >= VDIM) return;
    float m = ws[WS_RED], ls = ws[WS_RED + 1];
    out[i] = ws[WS_OLOG + i] - m - ls;
}

extern "C" void kernel_launch(void* const* d_in, const int* in_sizes, int n_in,
                              void* d_out, int out_size, void* d_ws, size_t ws_size,
                              hipStream_t stream) {
    const int*   idx    = (const int*)d_in[0];
    const float* hidden = (const float*)d_in[1];
    const float* enc    = (const float*)d_in[2];
    const float* emb    = (const float*)d_in[3];
    const float* attn_W = (const float*)d_in[4];
    const float* attn_b = (const float*)d_in[5];
    const float* comb_W = (const float*)d_in[6];
    const float* comb_b = (const float*)d_in[7];
    const float* W_ih   = (const float*)d_in[8];
    const float* W_hh   = (const float*)d_in[9];
    const float* b_ih   = (const float*)d_in[10];
    const float* b_hh   = (const float*)d_in[11];
    const float* out_W  = (const float*)d_in[12];
    const float* out_b  = (const float*)d_in[13];

    float* out  = (float*)d_out;                 // [V logits][H h_new][L attn_w]
    float* ws   = (float*)d_ws;

    k_att<<<LDIM, 64, 0, stream>>>(idx, hidden, emb, attn_W, attn_b, ws);
    k_softmax_att<<<1, 512, 0, stream>>>(ws, out + VDIM + HDIM);
    k_ctx<<<64, 256, 0, stream>>>(enc, ws);
    k_combine<<<256, 256, 0, stream>>>(idx, emb, comb_W, comb_b, ws);
    k_gru<<<1536, 256, 0, stream>>>(hidden, W_ih, W_hh, b_ih, b_hh, ws);
    k_gate<<<4, 256, 0, stream>>>(hidden, ws, out + VDIM);
    k_out<<<(VDIM + 3) / 4, 256, 0, stream>>>(out_W, out_b, ws);
    k_red<<<1, 1024, 0, stream>>>(ws);
    k_final<<<(VDIM + 255) / 256, 256, 0, stream>>>(ws, out);
}